// Round 6
// baseline (382.309 us; speedup 1.0000x reference)
//
#include <hip/hip_runtime.h>
#include <hip/hip_fp16.h>

#define NH   16
#define SQL  1024
#define SKV  4096
#define HD   128
#define TK   64
#define NBLK 1024   // dsa grid = exactly 4 blocks/CU * 256 CU -> co-resident

typedef _Float16 h2_t  __attribute__((ext_vector_type(2)));
typedef float    f32x4 __attribute__((ext_vector_type(4)));   // nontemporal-safe

__device__ __forceinline__ unsigned pkh(float x, float y) {
    return (unsigned)__half_as_ushort(__float2half(x)) |
           ((unsigned)__half_as_ushort(__float2half(y)) << 16);
}

// ---- kernel 1: convert heads 0..7 (round-0 set) XCD-locally and zero the
// grid-barrier counter for kernel 2. 2048 blocks x 256 thr, 16 elems/thr.
__global__ __launch_bounds__(256) void cvt_r0(
    const float* __restrict__ k, const float* __restrict__ v,
    unsigned short* __restrict__ kh, unsigned short* __restrict__ vh,
    unsigned* ctr)
{
    if (blockIdx.x == 0 && threadIdx.x == 0) *ctr = 0u;  // fresh every iter
    const int b   = blockIdx.x;
    const int x   = b & 7;            // head 0..7 (== XCD of the consumer)
    const int j   = b >> 3;           // 0..255
    const int isK = j >> 7;           // V first, K last (K freshest in L2)
    const int sl  = j & 127;
    const float*    src = isK ? k  : v;
    unsigned short* dst = isK ? kh : vh;
    const size_t base = (size_t)x * SKV * HD + (size_t)sl * 4096
                      + (size_t)threadIdx.x * 16;
    const f32x4* s4 = (const f32x4*)(src + base);
    uint4*       d4 = (uint4*)(dst + base);
#pragma unroll
    for (int u = 0; u < 2; ++u) {
        f32x4 a = __builtin_nontemporal_load(s4 + 2 * u);
        f32x4 c = __builtin_nontemporal_load(s4 + 2 * u + 1);
        uint4 o;
        o.x = pkh(a.x, a.y);
        o.y = pkh(a.z, a.w);
        o.z = pkh(c.x, c.y);
        o.w = pkh(c.z, c.w);
        d4[u] = o;
    }
}

// one full query: K-gathers+dot -> LDS transpose -> fused softmax ->
// V-gathers staged in regs (latency hidden under softmax) -> PV -> store.
// This is the verified r0 core (passed, absmax 7.8e-3).
__device__ __forceinline__ void attn_one(
    const float* __restrict__ q, const unsigned short* __restrict__ kb,
    const unsigned short* __restrict__ vb, float* __restrict__ out,
    int h, int s, int tIdx, float tSc,
    float (*scrw)[17], int lane, int quad, int l16)
{
    const float* qp = q + (size_t)(h * SQL + s) * HD + 8 * l16;
    const f32x4 qa = __builtin_nontemporal_load((const f32x4*)qp);
    const f32x4 qb = __builtin_nontemporal_load((const f32x4*)qp + 1);
    h2_t q0 = {(_Float16)qa.x, (_Float16)qa.y};
    h2_t q1 = {(_Float16)qa.z, (_Float16)qa.w};
    h2_t q2 = {(_Float16)qb.x, (_Float16)qb.y};
    h2_t q3 = {(_Float16)qb.z, (_Float16)qb.w};

    float part[16];
#pragma unroll
    for (int i = 0; i < 16; ++i) {
        const size_t row = (size_t)__shfl(tIdx, 4 * i + quad);
        uint4 kw = *(const uint4*)(kb + row * HD + 8 * l16);
        float d = 0.f;
#if __has_builtin(__builtin_amdgcn_fdot2)
        d = __builtin_amdgcn_fdot2(q0, __builtin_bit_cast(h2_t, kw.x), d, false);
        d = __builtin_amdgcn_fdot2(q1, __builtin_bit_cast(h2_t, kw.y), d, false);
        d = __builtin_amdgcn_fdot2(q2, __builtin_bit_cast(h2_t, kw.z), d, false);
        d = __builtin_amdgcn_fdot2(q3, __builtin_bit_cast(h2_t, kw.w), d, false);
#else
        {
            float2 k0 = __half22float2(__builtin_bit_cast(__half2, kw.x));
            float2 k1 = __half22float2(__builtin_bit_cast(__half2, kw.y));
            float2 k2 = __half22float2(__builtin_bit_cast(__half2, kw.z));
            float2 k3 = __half22float2(__builtin_bit_cast(__half2, kw.w));
            d  = qa.x * k0.x + qa.y * k0.y + qa.z * k1.x + qa.w * k1.y;
            d += qb.x * k2.x + qb.y * k2.y + qb.z * k3.x + qb.w * k3.y;
        }
#endif
        part[i] = d;
    }

    // issue ALL V gathers now; latency hides behind transpose+softmax
    uint4 vw[16];
#pragma unroll
    for (int i = 0; i < 16; ++i) {
        const size_t row = (size_t)__shfl(tIdx, 4 * i + quad);
        vw[i] = *(const uint4*)(vb + row * HD + 8 * l16);
    }

    // wave-private LDS transpose (no barrier): lane j ends owning t=j
#pragma unroll
    for (int i = 0; i < 16; ++i) scrw[4 * i + quad][l16] = part[i];
    float acc = 0.f;
#pragma unroll
    for (int m = 0; m < 16; ++m) acc += scrw[lane][m];
    acc *= 0.08838834764831845f;                       // 1/sqrt(128)

    // fused softmax * topk_scores, renormalized:
    // w_t = e_t*ts_t / (sum(e*ts) + 1e-12*sum(e))
    float mx = acc;
#pragma unroll
    for (int off = 32; off; off >>= 1) mx = fmaxf(mx, __shfl_xor(mx, off));
    const float e   = __expf(acc - mx);
    const float ets = e * tSc;
    float se = e, sets = ets;
#pragma unroll
    for (int off = 32; off; off >>= 1) {
        se   += __shfl_xor(se, off);
        sets += __shfl_xor(sets, off);
    }
    const float w = ets / (sets + 1e-12f * se);
    const unsigned wpk = __builtin_bit_cast(unsigned, __float2half2_rn(w));

    // PV from registers; weight broadcast via __shfl
    __half2 o0 = __float2half2_rn(0.f);
    __half2 o1 = o0, o2 = o0, o3 = o0;
#pragma unroll
    for (int i = 0; i < 16; ++i) {
        const __half2 w2 = __builtin_bit_cast(__half2, __shfl(wpk, 4 * i + quad));
        o0 = __hfma2(w2, __builtin_bit_cast(__half2, vw[i].x), o0);
        o1 = __hfma2(w2, __builtin_bit_cast(__half2, vw[i].y), o1);
        o2 = __hfma2(w2, __builtin_bit_cast(__half2, vw[i].z), o2);
        o3 = __hfma2(w2, __builtin_bit_cast(__half2, vw[i].w), o3);
    }

    __half2 oo[4] = {o0, o1, o2, o3};
#pragma unroll
    for (int j = 0; j < 4; ++j) {
        unsigned u = __builtin_bit_cast(unsigned, oo[j]);
        oo[j] = __hadd2(oo[j], __builtin_bit_cast(__half2, __shfl_xor(u, 16)));
        u = __builtin_bit_cast(unsigned, oo[j]);
        oo[j] = __hadd2(oo[j], __builtin_bit_cast(__half2, __shfl_xor(u, 32)));
    }

    if (quad == 0) {
        float2 f0 = __half22float2(oo[0]);
        float2 f1 = __half22float2(oo[1]);
        float2 f2 = __half22float2(oo[2]);
        float2 f3 = __half22float2(oo[3]);
        float* op = out + (size_t)(h * SQL + s) * HD + 8 * l16;
        f32x4 w0 = {f0.x, f0.y, f1.x, f1.y};
        f32x4 w1 = {f2.x, f2.y, f3.x, f3.y};
        __builtin_nontemporal_store(w0, (f32x4*)op);
        __builtin_nontemporal_store(w1, (f32x4*)op + 1);
    }
}

// ---- kernel 2: round-0 attention (heads 0..7, fp16 ready) with the
// round-1 conversion (heads 8..15) interleaved so its HBM traffic hides
// under the gather pipeline; hand-rolled grid barrier (all NBLK blocks
// co-resident by capacity: 4/CU cap, grid == 4*256); round-1 attention.
// Producer and consumer of each round-1 head are same-XCD blocks; the
// handshake is device-scope atomic + threadfence.
__global__ __launch_bounds__(256, 4) void dsa_ov(
    const float* __restrict__ q, const float* __restrict__ k,
    const float* __restrict__ v, const int* __restrict__ tidx,
    const float* __restrict__ tsc, float* __restrict__ out,
    unsigned short* __restrict__ kh, unsigned short* __restrict__ vh,
    unsigned* ctr)
{
    __shared__ float scr[4][TK][17];

    const int tid  = threadIdx.x;
    const int wv   = tid >> 6;
    const int lane = tid & 63;
    const int quad = lane >> 4;
    const int l16  = lane & 15;
    const int bi   = blockIdx.x;
    const int x    = bi & 7;               // XCD / round-0 head
    const int blkx = bi >> 3;              // 0..127
    const int s0   = blkx * 8 + wv * 2;    // this wave's queries

    int   tIdx[2];
    float tSc[2];
#pragma unroll
    for (int qi = 0; qi < 2; ++qi) {
        tIdx[qi] = tidx[(s0 + qi) * TK + lane];
        tSc[qi]  = tsc[(s0 + qi) * TK + lane];
    }

    const int h8 = x | 8;
    // this block's round-1 conversion slice: 4096 elems of K + 4096 of V
    const size_t cbase = (size_t)h8 * SKV * HD + (size_t)blkx * 4096
                       + (size_t)tid * 16;

    const unsigned short* kb0 = kh + (size_t)x * SKV * HD;
    const unsigned short* vb0 = vh + (size_t)x * SKV * HD;

    // ---- round 0, query 0
    attn_one(q, kb0, vb0, out, x, s0, tIdx[0], tSc[0], scr[wv], lane, quad, l16);

    // issue conv-K loads; latency hides under q1's gather compute (T14)
    const f32x4* ks4 = (const f32x4*)(k + cbase);
    f32x4 ck0 = __builtin_nontemporal_load(ks4);
    f32x4 ck1 = __builtin_nontemporal_load(ks4 + 1);
    f32x4 ck2 = __builtin_nontemporal_load(ks4 + 2);
    f32x4 ck3 = __builtin_nontemporal_load(ks4 + 3);

    // ---- round 0, query 1
    attn_one(q, kb0, vb0, out, x, s0 + 1, tIdx[1], tSc[1], scr[wv], lane, quad, l16);

    // conv-K store; issue conv-V loads
    {
        uint4* d4 = (uint4*)(kh + cbase);
        uint4 o0, o1;
        o0.x = pkh(ck0.x, ck0.y); o0.y = pkh(ck0.z, ck0.w);
        o0.z = pkh(ck1.x, ck1.y); o0.w = pkh(ck1.z, ck1.w);
        o1.x = pkh(ck2.x, ck2.y); o1.y = pkh(ck2.z, ck2.w);
        o1.z = pkh(ck3.x, ck3.y); o1.w = pkh(ck3.z, ck3.w);
        d4[0] = o0; d4[1] = o1;
    }
    {
        const f32x4* vs4 = (const f32x4*)(v + cbase);
        f32x4 a0 = __builtin_nontemporal_load(vs4);
        f32x4 a1 = __builtin_nontemporal_load(vs4 + 1);
        f32x4 a2 = __builtin_nontemporal_load(vs4 + 2);
        f32x4 a3 = __builtin_nontemporal_load(vs4 + 3);
        uint4* d4 = (uint4*)(vh + cbase);
        uint4 o0, o1;
        o0.x = pkh(a0.x, a0.y); o0.y = pkh(a0.z, a0.w);
        o0.z = pkh(a1.x, a1.y); o0.w = pkh(a1.z, a1.w);
        o1.x = pkh(a2.x, a2.y); o1.y = pkh(a2.z, a2.w);
        o1.z = pkh(a3.x, a3.y); o1.w = pkh(a3.z, a3.w);
        d4[0] = o0; d4[1] = o1;
    }

    // ---- grid barrier (bounded spin: degrades to visible wrong answer,
    // never a hang, if the residency assumption is ever violated)
    __syncthreads();
    if (tid == 0) {
        __threadfence();   // push conv stores to device scope (L2)
        __hip_atomic_fetch_add(ctr, 1u, __ATOMIC_ACQ_REL,
                               __HIP_MEMORY_SCOPE_AGENT);
        int spins = 0;
        while (__hip_atomic_load(ctr, __ATOMIC_ACQUIRE,
                                 __HIP_MEMORY_SCOPE_AGENT) < (unsigned)NBLK) {
            __builtin_amdgcn_s_sleep(8);
            if (++spins > 100000) break;   // ~10 ms safety valve
        }
        __threadfence();
    }
    __syncthreads();

    // ---- round 1: head x+8 (fp16 written by same-XCD blocks)
    const unsigned short* kb1 = kh + (size_t)h8 * SKV * HD;
    const unsigned short* vb1 = vh + (size_t)h8 * SKV * HD;
    attn_one(q, kb1, vb1, out, h8, s0,     tIdx[0], tSc[0], scr[wv], lane, quad, l16);
    attn_one(q, kb1, vb1, out, h8, s0 + 1, tIdx[1], tSc[1], scr[wv], lane, quad, l16);
}

// ---- fp32 fallback if workspace too small ----
__global__ __launch_bounds__(256) void dsa_fp32(
    const float* __restrict__ q, const float* __restrict__ k,
    const float* __restrict__ v, const int* __restrict__ tidx,
    const float* __restrict__ tsc, float* __restrict__ out)
{
    __shared__ int   idxs[4][TK];
    __shared__ float wsc[4][TK];
    const int tid = threadIdx.x, wv = tid >> 6, lane = tid & 63;
    const int half = lane >> 5, l32 = lane & 31, bi = blockIdx.x;
    const int h = ((bi & 7) << 1) | ((bi >> 3) & 1);
    const int s = ((bi >> 4) << 2) + wv;
    const float* qp = q + (size_t)(h * SQL + s) * HD;
    const float4 qf = *(const float4*)(qp + 4 * l32);
    const float t_sc = tsc[s * TK + lane];
    idxs[wv][lane] = tidx[s * TK + lane];
    const float* kb = k + (size_t)h * SKV * HD;
#pragma unroll 4
    for (int i = 0; i < TK / 2; ++i) {
        const int t = 2 * i + half, row = idxs[wv][t];
        float4 k4 = *(const float4*)(kb + (size_t)row * HD + 4 * l32);
        float d = k4.x * qf.x + k4.y * qf.y + k4.z * qf.z + k4.w * qf.w;
        d += __shfl_xor(d, 16); d += __shfl_xor(d, 8); d += __shfl_xor(d, 4);
        d += __shfl_xor(d, 2);  d += __shfl_xor(d, 1);
        if (l32 == 0) wsc[wv][t] = d;
    }
    float acc = wsc[wv][lane] * 0.08838834764831845f;
    float m = acc;
#pragma unroll
    for (int off = 32; off; off >>= 1) m = fmaxf(m, __shfl_xor(m, off));
    const float e = __expf(acc - m), ets = e * t_sc;
    float se = e, sets = ets;
#pragma unroll
    for (int off = 32; off; off >>= 1) { se += __shfl_xor(se, off); sets += __shfl_xor(sets, off); }
    wsc[wv][lane] = ets / (sets + 1e-12f * se);
    const float* vbp = v + (size_t)h * SKV * HD;
    float4 o = make_float4(0.f, 0.f, 0.f, 0.f);
#pragma unroll 4
    for (int i = 0; i < TK / 2; ++i) {
        const int t = 2 * i + half, row = idxs[wv][t];
        const float wt = wsc[wv][t];
        float4 v4 = *(const float4*)(vbp + (size_t)row * HD + 4 * l32);
        o.x += wt * v4.x; o.y += wt * v4.y; o.z += wt * v4.z; o.w += wt * v4.w;
    }
    o.x += __shfl_xor(o.x, 32); o.y += __shfl_xor(o.y, 32);
    o.z += __shfl_xor(o.z, 32); o.w += __shfl_xor(o.w, 32);
    if (half == 0) *(float4*)(out + (size_t)(h * SQL + s) * HD + 4 * l32) = o;
}

extern "C" void kernel_launch(void* const* d_in, const int* in_sizes, int n_in,
                              void* d_out, int out_size, void* d_ws, size_t ws_size,
                              hipStream_t stream) {
    const float* q  = (const float*)d_in[0];
    const float* k  = (const float*)d_in[1];
    const float* v  = (const float*)d_in[2];
    const int*   ti = (const int*)d_in[3];
    const float* ts = (const float*)d_in[4];
    float* out = (float*)d_out;

    const size_t nkv   = (size_t)NH * SKV * HD;              // 8.4M elems each
    const size_t fp16b = 2 * nkv * sizeof(unsigned short);   // 33.6 MB
    const size_t need  = fp16b + 256;                        // + barrier ctr
    if (ws_size >= need) {
        unsigned short* kh = (unsigned short*)d_ws;
        unsigned short* vh = kh + nkv;
        unsigned* ctr = (unsigned*)((char*)d_ws + fp16b);    // 256B-aligned

        cvt_r0<<<dim3(2048), dim3(256), 0, stream>>>(k, v, kh, vh, ctr);
        dsa_ov<<<dim3(NBLK), dim3(256), 0, stream>>>(q, k, v, ti, ts, out,
                                                     kh, vh, ctr);
    } else {
        dsa_fp32<<<dim3(4096), dim3(256), 0, stream>>>(q, k, v, ti, ts, out);
    }
}

// Round 8
// 162.690 us; speedup vs baseline: 2.3499x; 2.3499x over previous
//
#include <hip/hip_runtime.h>
#include <hip/hip_fp16.h>

#define NH  16
#define SQL 1024
#define SKV 4096
#define HD  128
#define TK  64

typedef _Float16 h2_t  __attribute__((ext_vector_type(2)));
typedef float    f32x4 __attribute__((ext_vector_type(4)));   // nontemporal-safe

__device__ __forceinline__ unsigned pkh(float x, float y) {
    return (unsigned)__half_as_ushort(__float2half(x)) |
           ((unsigned)__half_as_ushort(__float2half(y)) << 16);
}

// ---- convert: K fp32 -> int8 (per-row absmax scale, scores path),
//               V fp32 -> fp16 (output path).
// blocks [0,4096): K — 16 rows/block, one 16-lane group per row.
// blocks [4096,8192): V — 8 elems/thread streaming pack.
__global__ __launch_bounds__(256) void cvt_mixed(
    const float* __restrict__ k, const float* __restrict__ v,
    signed char* __restrict__ kq, float* __restrict__ ksc,
    unsigned short* __restrict__ vh)
{
    int b = blockIdx.x;
    if (b < 4096) {   // ---- K -> int8 + scale
        const int g   = threadIdx.x >> 4;     // row group 0..15
        const int l   = threadIdx.x & 15;     // lane in row, dims 8l..8l+7
        const int row = b * 16 + g;           // global row in [0, NH*SKV)
        const float* src = k + (size_t)row * HD + 8 * l;
        const f32x4 a = __builtin_nontemporal_load((const f32x4*)src);
        const f32x4 c = __builtin_nontemporal_load((const f32x4*)src + 1);

        // row absmax over the 16-lane group
        float m = fmaxf(fmaxf(fmaxf(fabsf(a.x), fabsf(a.y)),
                              fmaxf(fabsf(a.z), fabsf(a.w))),
                        fmaxf(fmaxf(fabsf(c.x), fabsf(c.y)),
                              fmaxf(fabsf(c.z), fabsf(c.w))));
        m = fmaxf(m, __shfl_xor(m, 1));
        m = fmaxf(m, __shfl_xor(m, 2));
        m = fmaxf(m, __shfl_xor(m, 4));
        m = fmaxf(m, __shfl_xor(m, 8));

        const float scale  = m * (1.0f / 127.0f);
        const float rscale = (m > 0.f) ? 127.0f / m : 0.f;

        int q0 = (int)rintf(a.x * rscale), q1 = (int)rintf(a.y * rscale);
        int q2 = (int)rintf(a.z * rscale), q3 = (int)rintf(a.w * rscale);
        int q4 = (int)rintf(c.x * rscale), q5 = (int)rintf(c.y * rscale);
        int q6 = (int)rintf(c.z * rscale), q7 = (int)rintf(c.w * rscale);
        uint2 o;
        o.x = (unsigned)(q0 & 0xFF) | ((unsigned)(q1 & 0xFF) << 8) |
              ((unsigned)(q2 & 0xFF) << 16) | ((unsigned)(q3 & 0xFF) << 24);
        o.y = (unsigned)(q4 & 0xFF) | ((unsigned)(q5 & 0xFF) << 8) |
              ((unsigned)(q6 & 0xFF) << 16) | ((unsigned)(q7 & 0xFF) << 24);
        *(uint2*)(kq + (size_t)row * HD + 8 * l) = o;
        if (l == 0) ksc[row] = scale;
    } else {          // ---- V -> fp16
        b -= 4096;
        const size_t i = (size_t)b * 256 + threadIdx.x;
        const float4* s4 = (const float4*)v;
        float4 a = s4[2 * i], c = s4[2 * i + 1];
        uint4 o;
        o.x = pkh(a.x, a.y);
        o.y = pkh(a.z, a.w);
        o.z = pkh(c.x, c.y);
        o.w = pkh(c.z, c.w);
        ((uint4*)vh)[i] = o;
    }
}

// ---- phase-separated attention (r2 structure; K path int8+scale):
// grid 512 blocks (2/CU, co-resident). Block b -> XCD b&7.
// Round 0: head b&7, round 1: head (b&7)+8. Phase A = K-gathers (int8,
// 128 B/row + 4 B scale) + softmax for 4 queries/wave (weights in
// registers), barrier, phase B = V-gathers (fp16) + PV. Per-XCD working
// set per head = 0.54 MB K + 2.1 MB V -> fully L2-resident.
__global__ __launch_bounds__(256, 2) void dsa_k8i(
    const float* __restrict__ q, const signed char* __restrict__ kq,
    const float* __restrict__ ksc, const unsigned short* __restrict__ vh,
    const int* __restrict__ tidx, const float* __restrict__ tsc,
    float* __restrict__ out)
{
    __shared__ float scr[4][TK][17];   // transpose buffer; wave-private rows

    const int tid  = threadIdx.x;
    const int wv   = tid >> 6;
    const int lane = tid & 63;
    const int quad = lane >> 4;    // which of 4 gathered rows this 16-lane group loads
    const int l16  = lane & 15;    // dims 8*l16 .. 8*l16+7
    const int bi   = blockIdx.x;
    const int xcd  = bi & 7;
    const int tile = bi >> 3;              // 0..63, 16 queries per tile
    const int sb   = tile * 16 + wv * 4;   // first of this wave's 4 queries

    // topk idx/scores are head-independent: load once, reuse both rounds
    int   tIdx[4];
    float tSc[4];
#pragma unroll
    for (int qi = 0; qi < 4; ++qi) {
        tIdx[qi] = tidx[(sb + qi) * TK + lane];
        tSc[qi]  = tsc[(sb + qi) * TK + lane];
    }

    for (int rnd = 0; rnd < 2; ++rnd) {
        const int h = xcd | (rnd << 3);
        const signed char*    kb = kq  + (size_t)h * SKV * HD;
        const float*          ks = ksc + (size_t)h * SKV;
        const unsigned short* vb = vh  + (size_t)h * SKV * HD;
        unsigned wpk[4];   // per-query softmax weight (lane t owns t), packed half2

        // -------- phase A: K gathers (int8 + row scale), scores, softmax -----
#pragma unroll
        for (int qi = 0; qi < 4; ++qi) {
            const int s = sb + qi;
            // q fragment: 8 dims (fp32, nontemporal: don't evict K/V from L2)
            const float* qp = q + (size_t)(h * SQL + s) * HD + 8 * l16;
            const f32x4 qa = __builtin_nontemporal_load((const f32x4*)qp);
            const f32x4 qb = __builtin_nontemporal_load((const f32x4*)qp + 1);

            float part[16];
#pragma unroll
            for (int i = 0; i < 16; ++i) {
                const size_t row = (size_t)__shfl(tIdx[qi], 4 * i + quad);
                const uint2 kw = *(const uint2*)(kb + row * HD + 8 * l16);
                const float sc = ks[row];
                const int w0 = (int)kw.x, w1 = (int)kw.y;
                float d;
                d = qa.x * (float)(signed char)(w0);
                d = fmaf(qa.y, (float)(signed char)(w0 >> 8),  d);
                d = fmaf(qa.z, (float)(signed char)(w0 >> 16), d);
                d = fmaf(qa.w, (float)(w0 >> 24),              d);
                d = fmaf(qb.x, (float)(signed char)(w1),       d);
                d = fmaf(qb.y, (float)(signed char)(w1 >> 8),  d);
                d = fmaf(qb.z, (float)(signed char)(w1 >> 16), d);
                d = fmaf(qb.w, (float)(w1 >> 24),              d);
                part[i] = d * sc;
            }

            // one LDS transpose (wave-private rows -> no barrier): lane j ends
            // up owning the score for t=j, exactly the softmax layout.
#pragma unroll
            for (int i = 0; i < 16; ++i) scr[wv][4 * i + quad][l16] = part[i];
            float acc = 0.f;
#pragma unroll
            for (int m = 0; m < 16; ++m) acc += scr[wv][lane][m];
            acc *= 0.08838834764831845f;                       // 1/sqrt(128)

            // fused softmax * topk_scores, renormalized:
            // w_t = e_t*ts_t / (sum(e*ts) + 1e-12*sum(e))
            float mx = acc;
#pragma unroll
            for (int off = 32; off; off >>= 1) mx = fmaxf(mx, __shfl_xor(mx, off));
            const float e   = __expf(acc - mx);
            const float ets = e * tSc[qi];
            float se = e, sets = ets;
#pragma unroll
            for (int off = 32; off; off >>= 1) {
                se   += __shfl_xor(se, off);
                sets += __shfl_xor(sets, off);
            }
            const float w = ets / (sets + 1e-12f * se);
            wpk[qi] = __builtin_bit_cast(unsigned, __float2half2_rn(w));
        }

        __syncthreads();   // keep the block's waves phase-aligned (K done, V next)

        // ---------------- phase B: V gathers (fp16) + PV + store -------------
#pragma unroll
        for (int qi = 0; qi < 4; ++qi) {
            const int s = sb + qi;
            __half2 o0 = __float2half2_rn(0.f);
            __half2 o1 = o0, o2 = o0, o3 = o0;
#pragma unroll
            for (int i = 0; i < 16; ++i) {
                const size_t row = (size_t)__shfl(tIdx[qi], 4 * i + quad);
                uint4 vw = *(const uint4*)(vb + row * HD + 8 * l16);
                const __half2 w2 =
                    __builtin_bit_cast(__half2, __shfl(wpk[qi], 4 * i + quad));
                o0 = __hfma2(w2, __builtin_bit_cast(__half2, vw.x), o0);
                o1 = __hfma2(w2, __builtin_bit_cast(__half2, vw.y), o1);
                o2 = __hfma2(w2, __builtin_bit_cast(__half2, vw.z), o2);
                o3 = __hfma2(w2, __builtin_bit_cast(__half2, vw.w), o3);
            }

            // quads hold disjoint t-subsets of the same dims -> combine fp16 pairs
            __half2 oo[4] = {o0, o1, o2, o3};
#pragma unroll
            for (int j = 0; j < 4; ++j) {
                unsigned u = __builtin_bit_cast(unsigned, oo[j]);
                oo[j] = __hadd2(oo[j], __builtin_bit_cast(__half2, __shfl_xor(u, 16)));
                u = __builtin_bit_cast(unsigned, oo[j]);
                oo[j] = __hadd2(oo[j], __builtin_bit_cast(__half2, __shfl_xor(u, 32)));
            }

            if (quad == 0) {
                float2 f0 = __half22float2(oo[0]);
                float2 f1 = __half22float2(oo[1]);
                float2 f2 = __half22float2(oo[2]);
                float2 f3 = __half22float2(oo[3]);
                float* op = out + (size_t)(h * SQL + s) * HD + 8 * l16;
                f32x4 w0 = {f0.x, f0.y, f1.x, f1.y};
                f32x4 w1 = {f2.x, f2.y, f3.x, f3.y};
                __builtin_nontemporal_store(w0, (f32x4*)op);
                __builtin_nontemporal_store(w1, (f32x4*)op + 1);
            }
        }
        if (rnd == 0) __syncthreads();   // don't start head x+8 K-gathers
                                         // while head x V-phase still runs
    }
}

// ---- fp32 fallback if workspace too small ----
__global__ __launch_bounds__(256) void dsa_fp32(
    const float* __restrict__ q, const float* __restrict__ k,
    const float* __restrict__ v, const int* __restrict__ tidx,
    const float* __restrict__ tsc, float* __restrict__ out)
{
    __shared__ int   idxs[4][TK];
    __shared__ float wsc[4][TK];
    const int tid = threadIdx.x, wv = tid >> 6, lane = tid & 63;
    const int half = lane >> 5, l32 = lane & 31, bi = blockIdx.x;
    const int h = ((bi & 7) << 1) | ((bi >> 3) & 1);
    const int s = ((bi >> 4) << 2) + wv;
    const float* qp = q + (size_t)(h * SQL + s) * HD;
    const float4 qf = *(const float4*)(qp + 4 * l32);
    const float t_sc = tsc[s * TK + lane];
    idxs[wv][lane] = tidx[s * TK + lane];
    const float* kb = k + (size_t)h * SKV * HD;
#pragma unroll 4
    for (int i = 0; i < TK / 2; ++i) {
        const int t = 2 * i + half, row = idxs[wv][t];
        float4 k4 = *(const float4*)(kb + (size_t)row * HD + 4 * l32);
        float d = k4.x * qf.x + k4.y * qf.y + k4.z * qf.z + k4.w * qf.w;
        d += __shfl_xor(d, 16); d += __shfl_xor(d, 8); d += __shfl_xor(d, 4);
        d += __shfl_xor(d, 2);  d += __shfl_xor(d, 1);
        if (l32 == 0) wsc[wv][t] = d;
    }
    float acc = wsc[wv][lane] * 0.08838834764831845f;
    float m = acc;
#pragma unroll
    for (int off = 32; off; off >>= 1) m = fmaxf(m, __shfl_xor(m, off));
    const float e = __expf(acc - m), ets = e * t_sc;
    float se = e, sets = ets;
#pragma unroll
    for (int off = 32; off; off >>= 1) { se += __shfl_xor(se, off); sets += __shfl_xor(sets, off); }
    wsc[wv][lane] = ets / (sets + 1e-12f * se);
    const float* vbp = v + (size_t)h * SKV * HD;
    float4 o = make_float4(0.f, 0.f, 0.f, 0.f);
#pragma unroll 4
    for (int i = 0; i < TK / 2; ++i) {
        const int t = 2 * i + half, row = idxs[wv][t];
        const float wt = wsc[wv][t];
        float4 v4 = *(const float4*)(vbp + (size_t)row * HD + 4 * l32);
        o.x += wt * v4.x; o.y += wt * v4.y; o.z += wt * v4.z; o.w += wt * v4.w;
    }
    o.x += __shfl_xor(o.x, 32); o.y += __shfl_xor(o.y, 32);
    o.z += __shfl_xor(o.z, 32); o.w += __shfl_xor(o.w, 32);
    if (half == 0) *(float4*)(out + (size_t)(h * SQL + s) * HD + 4 * l32) = o;
}

extern "C" void kernel_launch(void* const* d_in, const int* in_sizes, int n_in,
                              void* d_out, int out_size, void* d_ws, size_t ws_size,
                              hipStream_t stream) {
    const float* q  = (const float*)d_in[0];
    const float* k  = (const float*)d_in[1];
    const float* v  = (const float*)d_in[2];
    const int*   ti = (const int*)d_in[3];
    const float* ts = (const float*)d_in[4];
    float* out = (float*)d_out;

    const size_t nkv   = (size_t)NH * SKV * HD;                // 8.4M elems each
    const size_t scb   = (size_t)NH * SKV * sizeof(float);     // 256 KB scales
    const size_t need  = nkv + scb + nkv * sizeof(unsigned short);  // ~25.5 MB
    if (ws_size >= need) {
        signed char*    kq  = (signed char*)d_ws;
        float*          ksc = (float*)(kq + nkv);
        unsigned short* vh  = (unsigned short*)((char*)ksc + scb);
        cvt_mixed<<<dim3(8192), dim3(256), 0, stream>>>(k, v, kq, ksc, vh);
        dsa_k8i<<<dim3(512), dim3(256), 0, stream>>>(q, kq, ksc, vh, ti, ts, out);
    } else {
        dsa_fp32<<<dim3(4096), dim3(256), 0, stream>>>(q, k, v, ti, ts, out);
    }
}

// Round 9
// 139.217 us; speedup vs baseline: 2.7461x; 1.1686x over previous
//
#include <hip/hip_runtime.h>
#include <hip/hip_fp16.h>

#define NH  16
#define SQL 1024
#define SKV 4096
#define HD  128
#define TK  64

typedef _Float16 h2_t  __attribute__((ext_vector_type(2)));
typedef float    f32x4 __attribute__((ext_vector_type(4)));   // nontemporal-safe

#if __has_builtin(__builtin_amdgcn_sdot4)
#define HW_DOT4 1
#else
#define HW_DOT4 0
#endif

__device__ __forceinline__ unsigned pkh(float x, float y) {
    return (unsigned)__half_as_ushort(__float2half(x)) |
           ((unsigned)__half_as_ushort(__float2half(y)) << 16);
}

// ---- convert: K fp32 -> int8 (per-row absmax scale, scores path),
//               V fp32 -> fp16 (output path).  [verified r8 kernel]
// blocks [0,4096): K — 16 rows/block, one 16-lane group per row.
// blocks [4096,8192): V — 8 elems/thread streaming pack.
__global__ __launch_bounds__(256) void cvt_mixed(
    const float* __restrict__ k, const float* __restrict__ v,
    signed char* __restrict__ kq, float* __restrict__ ksc,
    unsigned short* __restrict__ vh)
{
    int b = blockIdx.x;
    if (b < 4096) {   // ---- K -> int8 + scale
        const int g   = threadIdx.x >> 4;     // row group 0..15
        const int l   = threadIdx.x & 15;     // lane in row, dims 8l..8l+7
        const int row = b * 16 + g;           // global row in [0, NH*SKV)
        const float* src = k + (size_t)row * HD + 8 * l;
        const f32x4 a = __builtin_nontemporal_load((const f32x4*)src);
        const f32x4 c = __builtin_nontemporal_load((const f32x4*)src + 1);

        float m = fmaxf(fmaxf(fmaxf(fabsf(a.x), fabsf(a.y)),
                              fmaxf(fabsf(a.z), fabsf(a.w))),
                        fmaxf(fmaxf(fabsf(c.x), fabsf(c.y)),
                              fmaxf(fabsf(c.z), fabsf(c.w))));
        m = fmaxf(m, __shfl_xor(m, 1));
        m = fmaxf(m, __shfl_xor(m, 2));
        m = fmaxf(m, __shfl_xor(m, 4));
        m = fmaxf(m, __shfl_xor(m, 8));

        const float scale  = m * (1.0f / 127.0f);
        const float rscale = (m > 0.f) ? 127.0f / m : 0.f;

        int q0 = (int)rintf(a.x * rscale), q1 = (int)rintf(a.y * rscale);
        int q2 = (int)rintf(a.z * rscale), q3 = (int)rintf(a.w * rscale);
        int q4 = (int)rintf(c.x * rscale), q5 = (int)rintf(c.y * rscale);
        int q6 = (int)rintf(c.z * rscale), q7 = (int)rintf(c.w * rscale);
        uint2 o;
        o.x = (unsigned)(q0 & 0xFF) | ((unsigned)(q1 & 0xFF) << 8) |
              ((unsigned)(q2 & 0xFF) << 16) | ((unsigned)(q3 & 0xFF) << 24);
        o.y = (unsigned)(q4 & 0xFF) | ((unsigned)(q5 & 0xFF) << 8) |
              ((unsigned)(q6 & 0xFF) << 16) | ((unsigned)(q7 & 0xFF) << 24);
        *(uint2*)(kq + (size_t)row * HD + 8 * l) = o;
        if (l == 0) ksc[row] = scale;
    } else {          // ---- V -> fp16
        b -= 4096;
        const size_t i = (size_t)b * 256 + threadIdx.x;
        const float4* s4 = (const float4*)v;
        float4 a = s4[2 * i], c = s4[2 * i + 1];
        uint4 o;
        o.x = pkh(a.x, a.y);
        o.y = pkh(a.z, a.w);
        o.z = pkh(c.x, c.y);
        o.w = pkh(c.z, c.w);
        ((uint4*)vh)[i] = o;
    }
}

// ---- phase-separated attention (r2 structure; K path int8 + sdot4,
// scales fully deferred out of the gather loop):
// grid 512 blocks (2/CU, co-resident). Block b -> XCD b&7.
// Round 0: head b&7, round 1: head (b&7)+8.
// Phase A per query: quantize q to int8 in-register (per-query absmax),
// 16 K-row gathers of 8 B each + 2 sdot4 per row (raw int32 partials),
// int transpose through LDS, scale applied ONCE per lane after the
// transpose (lane j owns t=j whose row index is lane-local tIdx).
// Barrier. Phase B: V-gathers (fp16) + PV, unchanged from r2.
__global__ __launch_bounds__(256, 2) void dsa_k8d(
    const float* __restrict__ q, const signed char* __restrict__ kq,
    const float* __restrict__ ksc, const unsigned short* __restrict__ vh,
    const int* __restrict__ tidx, const float* __restrict__ tsc,
    float* __restrict__ out)
{
    __shared__ float scr[4][TK][17];   // transpose buffer; wave-private rows

    const int tid  = threadIdx.x;
    const int wv   = tid >> 6;
    const int lane = tid & 63;
    const int quad = lane >> 4;    // which of 4 gathered rows this 16-lane group loads
    const int l16  = lane & 15;    // dims 8*l16 .. 8*l16+7
    const int bi   = blockIdx.x;
    const int xcd  = bi & 7;
    const int tile = bi >> 3;              // 0..63, 16 queries per tile
    const int sb   = tile * 16 + wv * 4;   // first of this wave's 4 queries

    // topk idx/scores are head-independent: load once, reuse both rounds
    int   tIdx[4];
    float tSc[4];
#pragma unroll
    for (int qi = 0; qi < 4; ++qi) {
        tIdx[qi] = tidx[(sb + qi) * TK + lane];
        tSc[qi]  = tsc[(sb + qi) * TK + lane];
    }

    for (int rnd = 0; rnd < 2; ++rnd) {
        const int h = xcd | (rnd << 3);
        const signed char*    kb = kq  + (size_t)h * SKV * HD;
        const float*          ks = ksc + (size_t)h * SKV;
        const unsigned short* vb = vh  + (size_t)h * SKV * HD;
        unsigned wpk[4];   // per-query softmax weight (lane t owns t), packed half2

        // -------- phase A: q-quantize, int8 K gathers + sdot4, softmax -------
#pragma unroll
        for (int qi = 0; qi < 4; ++qi) {
            const int s = sb + qi;
            // q fragment: 8 dims (fp32, nontemporal: don't evict K/V from L2)
            const float* qp = q + (size_t)(h * SQL + s) * HD + 8 * l16;
            const f32x4 qa = __builtin_nontemporal_load((const f32x4*)qp);
            const f32x4 qb = __builtin_nontemporal_load((const f32x4*)qp + 1);

            // own-lane K scale (for t = lane, used AFTER the transpose)
            const float myks = ks[tIdx[qi]];

#if HW_DOT4
            // per-query absmax over all 128 dims (16-lane group reduce;
            // quads hold identical q fragments, so the reduce is exact)
            float qm = fmaxf(fmaxf(fmaxf(fabsf(qa.x), fabsf(qa.y)),
                                   fmaxf(fabsf(qa.z), fabsf(qa.w))),
                             fmaxf(fmaxf(fabsf(qb.x), fabsf(qb.y)),
                                   fmaxf(fabsf(qb.z), fabsf(qb.w))));
            qm = fmaxf(qm, __shfl_xor(qm, 1));
            qm = fmaxf(qm, __shfl_xor(qm, 2));
            qm = fmaxf(qm, __shfl_xor(qm, 4));
            qm = fmaxf(qm, __shfl_xor(qm, 8));
            qm = fmaxf(qm, 1e-20f);
            const float qrs = 127.0f / qm;

            int a0 = (int)rintf(qa.x * qrs), a1 = (int)rintf(qa.y * qrs);
            int a2 = (int)rintf(qa.z * qrs), a3 = (int)rintf(qa.w * qrs);
            int b0 = (int)rintf(qb.x * qrs), b1 = (int)rintf(qb.y * qrs);
            int b2 = (int)rintf(qb.z * qrs), b3 = (int)rintf(qb.w * qrs);
            const int qd0 = (a0 & 0xFF) | ((a1 & 0xFF) << 8) |
                            ((a2 & 0xFF) << 16) | ((a3 & 0xFF) << 24);
            const int qd1 = (b0 & 0xFF) | ((b1 & 0xFF) << 8) |
                            ((b2 & 0xFF) << 16) | ((b3 & 0xFF) << 24);

            // full lane-local score scale: sc_k(t) * sc_q / sqrt(128)
            const float fullsc = myks * (qm * (1.0f / 127.0f))
                               * 0.08838834764831845f;

            int part[16];
#pragma unroll
            for (int i = 0; i < 16; ++i) {
                const size_t row = (size_t)__shfl(tIdx[qi], 4 * i + quad);
                const uint2 kw = *(const uint2*)(kb + row * HD + 8 * l16);
                int pd = __builtin_amdgcn_sdot4(qd0, (int)kw.x, 0, false);
                pd = __builtin_amdgcn_sdot4(qd1, (int)kw.y, pd, false);
                part[i] = pd;
            }

            // int transpose through the float LDS buffer (bitcast, exact):
            // lane j ends up owning the raw dot for t=j.
#pragma unroll
            for (int i = 0; i < 16; ++i)
                scr[wv][4 * i + quad][l16] = __builtin_bit_cast(float, part[i]);
            int iacc = 0;
#pragma unroll
            for (int m = 0; m < 16; ++m)
                iacc += __builtin_bit_cast(int, scr[wv][lane][m]);
            float acc = (float)iacc * fullsc;
#else
            // fallback: fp32 q × decoded int8 K, scale deferred per lane
            const float fullsc = myks * 0.08838834764831845f;
            float part[16];
#pragma unroll
            for (int i = 0; i < 16; ++i) {
                const size_t row = (size_t)__shfl(tIdx[qi], 4 * i + quad);
                const uint2 kw = *(const uint2*)(kb + row * HD + 8 * l16);
                const int w0 = (int)kw.x, w1 = (int)kw.y;
                float d;
                d = qa.x * (float)(signed char)(w0);
                d = fmaf(qa.y, (float)(signed char)(w0 >> 8),  d);
                d = fmaf(qa.z, (float)(signed char)(w0 >> 16), d);
                d = fmaf(qa.w, (float)(w0 >> 24),              d);
                d = fmaf(qb.x, (float)(signed char)(w1),       d);
                d = fmaf(qb.y, (float)(signed char)(w1 >> 8),  d);
                d = fmaf(qb.z, (float)(signed char)(w1 >> 16), d);
                d = fmaf(qb.w, (float)(w1 >> 24),              d);
                part[i] = d;
            }
#pragma unroll
            for (int i = 0; i < 16; ++i) scr[wv][4 * i + quad][l16] = part[i];
            float facc = 0.f;
#pragma unroll
            for (int m = 0; m < 16; ++m) facc += scr[wv][lane][m];
            float acc = facc * fullsc;
#endif

            // fused softmax * topk_scores, renormalized:
            // w_t = e_t*ts_t / (sum(e*ts) + 1e-12*sum(e))
            float mx = acc;
#pragma unroll
            for (int off = 32; off; off >>= 1) mx = fmaxf(mx, __shfl_xor(mx, off));
            const float e   = __expf(acc - mx);
            const float ets = e * tSc[qi];
            float se = e, sets = ets;
#pragma unroll
            for (int off = 32; off; off >>= 1) {
                se   += __shfl_xor(se, off);
                sets += __shfl_xor(sets, off);
            }
            const float w = ets / (sets + 1e-12f * se);
            wpk[qi] = __builtin_bit_cast(unsigned, __float2half2_rn(w));
        }

        __syncthreads();   // keep the block's waves phase-aligned (K done, V next)

        // ---------------- phase B: V gathers (fp16) + PV + store -------------
#pragma unroll
        for (int qi = 0; qi < 4; ++qi) {
            const int s = sb + qi;
            __half2 o0 = __float2half2_rn(0.f);
            __half2 o1 = o0, o2 = o0, o3 = o0;
#pragma unroll
            for (int i = 0; i < 16; ++i) {
                const size_t row = (size_t)__shfl(tIdx[qi], 4 * i + quad);
                uint4 vw = *(const uint4*)(vb + row * HD + 8 * l16);
                const __half2 w2 =
                    __builtin_bit_cast(__half2, __shfl(wpk[qi], 4 * i + quad));
                o0 = __hfma2(w2, __builtin_bit_cast(__half2, vw.x), o0);
                o1 = __hfma2(w2, __builtin_bit_cast(__half2, vw.y), o1);
                o2 = __hfma2(w2, __builtin_bit_cast(__half2, vw.z), o2);
                o3 = __hfma2(w2, __builtin_bit_cast(__half2, vw.w), o3);
            }

            // quads hold disjoint t-subsets of the same dims -> combine fp16 pairs
            __half2 oo[4] = {o0, o1, o2, o3};
#pragma unroll
            for (int j = 0; j < 4; ++j) {
                unsigned u = __builtin_bit_cast(unsigned, oo[j]);
                oo[j] = __hadd2(oo[j], __builtin_bit_cast(__half2, __shfl_xor(u, 16)));
                u = __builtin_bit_cast(unsigned, oo[j]);
                oo[j] = __hadd2(oo[j], __builtin_bit_cast(__half2, __shfl_xor(u, 32)));
            }

            if (quad == 0) {
                float2 f0 = __half22float2(oo[0]);
                float2 f1 = __half22float2(oo[1]);
                float2 f2 = __half22float2(oo[2]);
                float2 f3 = __half22float2(oo[3]);
                float* op = out + (size_t)(h * SQL + s) * HD + 8 * l16;
                f32x4 w0 = {f0.x, f0.y, f1.x, f1.y};
                f32x4 w1 = {f2.x, f2.y, f3.x, f3.y};
                __builtin_nontemporal_store(w0, (f32x4*)op);
                __builtin_nontemporal_store(w1, (f32x4*)op + 1);
            }
        }
        if (rnd == 0) __syncthreads();   // don't start head x+8 K-gathers
                                         // while head x V-phase still runs
    }
}

// ---- fp32 fallback if workspace too small ----
__global__ __launch_bounds__(256) void dsa_fp32(
    const float* __restrict__ q, const float* __restrict__ k,
    const float* __restrict__ v, const int* __restrict__ tidx,
    const float* __restrict__ tsc, float* __restrict__ out)
{
    __shared__ int   idxs[4][TK];
    __shared__ float wsc[4][TK];
    const int tid = threadIdx.x, wv = tid >> 6, lane = tid & 63;
    const int half = lane >> 5, l32 = lane & 31, bi = blockIdx.x;
    const int h = ((bi & 7) << 1) | ((bi >> 3) & 1);
    const int s = ((bi >> 4) << 2) + wv;
    const float* qp = q + (size_t)(h * SQL + s) * HD;
    const float4 qf = *(const float4*)(qp + 4 * l32);
    const float t_sc = tsc[s * TK + lane];
    idxs[wv][lane] = tidx[s * TK + lane];
    const float* kb = k + (size_t)h * SKV * HD;
#pragma unroll 4
    for (int i = 0; i < TK / 2; ++i) {
        const int t = 2 * i + half, row = idxs[wv][t];
        float4 k4 = *(const float4*)(kb + (size_t)row * HD + 4 * l32);
        float d = k4.x * qf.x + k4.y * qf.y + k4.z * qf.z + k4.w * qf.w;
        d += __shfl_xor(d, 16); d += __shfl_xor(d, 8); d += __shfl_xor(d, 4);
        d += __shfl_xor(d, 2);  d += __shfl_xor(d, 1);
        if (l32 == 0) wsc[wv][t] = d;
    }
    float acc = wsc[wv][lane] * 0.08838834764831845f;
    float m = acc;
#pragma unroll
    for (int off = 32; off; off >>= 1) m = fmaxf(m, __shfl_xor(m, off));
    const float e = __expf(acc - m), ets = e * t_sc;
    float se = e, sets = ets;
#pragma unroll
    for (int off = 32; off; off >>= 1) { se += __shfl_xor(se, off); sets += __shfl_xor(sets, off); }
    wsc[wv][lane] = ets / (sets + 1e-12f * se);
    const float* vbp = v + (size_t)h * SKV * HD;
    float4 o = make_float4(0.f, 0.f, 0.f, 0.f);
#pragma unroll 4
    for (int i = 0; i < TK / 2; ++i) {
        const int t = 2 * i + half, row = idxs[wv][t];
        const float wt = wsc[wv][t];
        float4 v4 = *(const float4*)(vbp + (size_t)row * HD + 4 * l32);
        o.x += wt * v4.x; o.y += wt * v4.y; o.z += wt * v4.z; o.w += wt * v4.w;
    }
    o.x += __shfl_xor(o.x, 32); o.y += __shfl_xor(o.y, 32);
    o.z += __shfl_xor(o.z, 32); o.w += __shfl_xor(o.w, 32);
    if (half == 0) *(float4*)(out + (size_t)(h * SQL + s) * HD + 4 * l32) = o;
}

extern "C" void kernel_launch(void* const* d_in, const int* in_sizes, int n_in,
                              void* d_out, int out_size, void* d_ws, size_t ws_size,
                              hipStream_t stream) {
    const float* q  = (const float*)d_in[0];
    const float* k  = (const float*)d_in[1];
    const float* v  = (const float*)d_in[2];
    const int*   ti = (const int*)d_in[3];
    const float* ts = (const float*)d_in[4];
    float* out = (float*)d_out;

    const size_t nkv   = (size_t)NH * SKV * HD;                // 8.4M elems each
    const size_t scb   = (size_t)NH * SKV * sizeof(float);     // 256 KB scales
    const size_t need  = nkv + scb + nkv * sizeof(unsigned short);  // ~25.5 MB
    if (ws_size >= need) {
        signed char*    kq  = (signed char*)d_ws;
        float*          ksc = (float*)(kq + nkv);
        unsigned short* vh  = (unsigned short*)((char*)ksc + scb);
        cvt_mixed<<<dim3(8192), dim3(256), 0, stream>>>(k, v, kq, ksc, vh);
        dsa_k8d<<<dim3(512), dim3(256), 0, stream>>>(q, kq, ksc, vh, ti, ts, out);
    } else {
        dsa_fp32<<<dim3(4096), dim3(256), 0, stream>>>(q, k, v, ti, ts, out);
    }
}

// Round 10
// 133.170 us; speedup vs baseline: 2.8708x; 1.0454x over previous
//
#include <hip/hip_runtime.h>
#include <hip/hip_fp16.h>

#define NH  16
#define SQL 1024
#define SKV 4096
#define HD  128
#define TK  64

typedef _Float16 h2_t  __attribute__((ext_vector_type(2)));
typedef float    f32x4 __attribute__((ext_vector_type(4)));   // nontemporal-safe

__device__ __forceinline__ unsigned pkh(float x, float y) {
    return (unsigned)__half_as_ushort(__float2half(x)) |
           ((unsigned)__half_as_ushort(__float2half(y)) << 16);
}

// ---- fp32 -> fp16 streaming cast, layout preserved [H][SKV][HD] ----
// blocks [0,4096): K, [4096,8192): V; 8 elems/thread
__global__ __launch_bounds__(256) void cvt_f16(
    const float* __restrict__ k, const float* __restrict__ v,
    unsigned short* __restrict__ kh, unsigned short* __restrict__ vh)
{
    int b = blockIdx.x;
    const float* src; unsigned short* dst;
    if (b < 4096) { src = k; dst = kh; }
    else          { src = v; dst = vh; b -= 4096; }
    const size_t i = (size_t)b * 256 + threadIdx.x;   // 8-elem chunk
    const float4* s4 = (const float4*)src;
    float4 a = s4[2 * i], c = s4[2 * i + 1];
    uint4 o;
    o.x = pkh(a.x, a.y);
    o.y = pkh(a.z, a.w);
    o.z = pkh(c.x, c.y);
    o.w = pkh(c.z, c.w);
    ((uint4*)dst)[i] = o;
}

// ---- phase-separated attention (best measured config, 133.5 us):
// grid 512 blocks (2/CU, co-resident). Block b -> XCD b&7.
// Round 0: head b&7, round 1: head (b&7)+8  => one head per XCD at a time.
// Within a round: phase A = K-gathers + softmax for 4 queries/wave
// (weights kept in registers), barrier, phase B = V-gathers + PV.
// Cost law (measured r3/r8/r9): gather time tracks wave-load instruction
// count, not bytes. 16 wave-loads/operand/query (4 rows each, 16 B/lane)
// is the structural minimum -> ~38 us; this kernel achieves it.
__global__ __launch_bounds__(256, 2) void dsa_phased(
    const float* __restrict__ q, const unsigned short* __restrict__ kh,
    const unsigned short* __restrict__ vh, const int* __restrict__ tidx,
    const float* __restrict__ tsc, float* __restrict__ out)
{
    __shared__ float scr[4][TK][17];   // transpose buffer; wave-private rows

    const int tid  = threadIdx.x;
    const int wv   = tid >> 6;
    const int lane = tid & 63;
    const int quad = lane >> 4;    // which of 4 gathered rows this 16-lane group loads
    const int l16  = lane & 15;    // dims 8*l16 .. 8*l16+7
    const int bi   = blockIdx.x;
    const int xcd  = bi & 7;
    const int tile = bi >> 3;              // 0..63, 16 queries per tile
    const int sb   = tile * 16 + wv * 4;   // first of this wave's 4 queries

    // topk idx/scores are head-independent: load once, reuse both rounds
    int   tIdx[4];
    float tSc[4];
#pragma unroll
    for (int qi = 0; qi < 4; ++qi) {
        tIdx[qi] = tidx[(sb + qi) * TK + lane];
        tSc[qi]  = tsc[(sb + qi) * TK + lane];
    }

    for (int rnd = 0; rnd < 2; ++rnd) {
        const int h = xcd | (rnd << 3);
        const unsigned short* kb = kh + (size_t)h * SKV * HD;
        const unsigned short* vb = vh + (size_t)h * SKV * HD;
        unsigned wpk[4];   // per-query softmax weight (lane t owns t), packed half2

        // ---------------- phase A: K gathers, scores, softmax ----------------
#pragma unroll
        for (int qi = 0; qi < 4; ++qi) {
            const int s = sb + qi;
            // q fragment: 8 dims (fp32, nontemporal: don't evict K from L2)
            const float* qp = q + (size_t)(h * SQL + s) * HD + 8 * l16;
            const f32x4 qa = __builtin_nontemporal_load((const f32x4*)qp);
            const f32x4 qb = __builtin_nontemporal_load((const f32x4*)qp + 1);
            h2_t q0 = {(_Float16)qa.x, (_Float16)qa.y};
            h2_t q1 = {(_Float16)qa.z, (_Float16)qa.w};
            h2_t q2 = {(_Float16)qb.x, (_Float16)qb.y};
            h2_t q3 = {(_Float16)qb.z, (_Float16)qb.w};

            float part[16];
#pragma unroll
            for (int i = 0; i < 16; ++i) {
                const size_t row = (size_t)__shfl(tIdx[qi], 4 * i + quad);
                uint4 kw = *(const uint4*)(kb + row * HD + 8 * l16);
                float d = 0.f;
#if __has_builtin(__builtin_amdgcn_fdot2)
                d = __builtin_amdgcn_fdot2(q0, __builtin_bit_cast(h2_t, kw.x), d, false);
                d = __builtin_amdgcn_fdot2(q1, __builtin_bit_cast(h2_t, kw.y), d, false);
                d = __builtin_amdgcn_fdot2(q2, __builtin_bit_cast(h2_t, kw.z), d, false);
                d = __builtin_amdgcn_fdot2(q3, __builtin_bit_cast(h2_t, kw.w), d, false);
#else
                {
                    float2 k0 = __half22float2(__builtin_bit_cast(__half2, kw.x));
                    float2 k1 = __half22float2(__builtin_bit_cast(__half2, kw.y));
                    float2 k2 = __half22float2(__builtin_bit_cast(__half2, kw.z));
                    float2 k3 = __half22float2(__builtin_bit_cast(__half2, kw.w));
                    d  = qa.x * k0.x + qa.y * k0.y + qa.z * k1.x + qa.w * k1.y;
                    d += qb.x * k2.x + qb.y * k2.y + qb.z * k3.x + qb.w * k3.y;
                }
#endif
                part[i] = d;
            }

            // one LDS transpose (wave-private rows -> no barrier): lane j ends
            // up owning the score for t=j, exactly the softmax layout.
#pragma unroll
            for (int i = 0; i < 16; ++i) scr[wv][4 * i + quad][l16] = part[i];
            float acc = 0.f;
#pragma unroll
            for (int m = 0; m < 16; ++m) acc += scr[wv][lane][m];
            acc *= 0.08838834764831845f;                       // 1/sqrt(128)

            // fused softmax * topk_scores, renormalized:
            // w_t = e_t*ts_t / (sum(e*ts) + 1e-12*sum(e))
            float mx = acc;
#pragma unroll
            for (int off = 32; off; off >>= 1) mx = fmaxf(mx, __shfl_xor(mx, off));
            const float e   = __expf(acc - mx);
            const float ets = e * tSc[qi];
            float se = e, sets = ets;
#pragma unroll
            for (int off = 32; off; off >>= 1) {
                se   += __shfl_xor(se, off);
                sets += __shfl_xor(sets, off);
            }
            const float w = ets / (sets + 1e-12f * se);
            wpk[qi] = __builtin_bit_cast(unsigned, __float2half2_rn(w));
        }

        __syncthreads();   // keep the block's waves phase-aligned (K done, V next)

        // ---------------- phase B: V gathers + PV + store ----------------
#pragma unroll
        for (int qi = 0; qi < 4; ++qi) {
            const int s = sb + qi;
            __half2 o0 = __float2half2_rn(0.f);
            __half2 o1 = o0, o2 = o0, o3 = o0;
#pragma unroll
            for (int i = 0; i < 16; ++i) {
                const size_t row = (size_t)__shfl(tIdx[qi], 4 * i + quad);
                uint4 vw = *(const uint4*)(vb + row * HD + 8 * l16);
                const __half2 w2 =
                    __builtin_bit_cast(__half2, __shfl(wpk[qi], 4 * i + quad));
                o0 = __hfma2(w2, __builtin_bit_cast(__half2, vw.x), o0);
                o1 = __hfma2(w2, __builtin_bit_cast(__half2, vw.y), o1);
                o2 = __hfma2(w2, __builtin_bit_cast(__half2, vw.z), o2);
                o3 = __hfma2(w2, __builtin_bit_cast(__half2, vw.w), o3);
            }

            // quads hold disjoint t-subsets of the same dims -> combine fp16 pairs
            __half2 oo[4] = {o0, o1, o2, o3};
#pragma unroll
            for (int j = 0; j < 4; ++j) {
                unsigned u = __builtin_bit_cast(unsigned, oo[j]);
                oo[j] = __hadd2(oo[j], __builtin_bit_cast(__half2, __shfl_xor(u, 16)));
                u = __builtin_bit_cast(unsigned, oo[j]);
                oo[j] = __hadd2(oo[j], __builtin_bit_cast(__half2, __shfl_xor(u, 32)));
            }

            if (quad == 0) {
                float2 f0 = __half22float2(oo[0]);
                float2 f1 = __half22float2(oo[1]);
                float2 f2 = __half22float2(oo[2]);
                float2 f3 = __half22float2(oo[3]);
                float* op = out + (size_t)(h * SQL + s) * HD + 8 * l16;
                f32x4 w0 = {f0.x, f0.y, f1.x, f1.y};
                f32x4 w1 = {f2.x, f2.y, f3.x, f3.y};
                __builtin_nontemporal_store(w0, (f32x4*)op);
                __builtin_nontemporal_store(w1, (f32x4*)op + 1);
            }
        }
        if (rnd == 0) __syncthreads();   // don't let head x+8 K-gathers start
                                         // while head x V-phase still runs
    }
}

// ---- fp32 fallback (round-1 kernel) if workspace too small ----
__global__ __launch_bounds__(256) void dsa_fp32(
    const float* __restrict__ q, const float* __restrict__ k,
    const float* __restrict__ v, const int* __restrict__ tidx,
    const float* __restrict__ tsc, float* __restrict__ out)
{
    __shared__ int   idxs[4][TK];
    __shared__ float wsc[4][TK];
    const int tid = threadIdx.x, wv = tid >> 6, lane = tid & 63;
    const int half = lane >> 5, l32 = lane & 31, bi = blockIdx.x;
    const int h = ((bi & 7) << 1) | ((bi >> 3) & 1);
    const int s = ((bi >> 4) << 2) + wv;
    const float* qp = q + (size_t)(h * SQL + s) * HD;
    const float4 qf = *(const float4*)(qp + 4 * l32);
    const float t_sc = tsc[s * TK + lane];
    idxs[wv][lane] = tidx[s * TK + lane];
    const float* kb = k + (size_t)h * SKV * HD;
#pragma unroll 4
    for (int i = 0; i < TK / 2; ++i) {
        const int t = 2 * i + half, row = idxs[wv][t];
        float4 k4 = *(const float4*)(kb + (size_t)row * HD + 4 * l32);
        float d = k4.x * qf.x + k4.y * qf.y + k4.z * qf.z + k4.w * qf.w;
        d += __shfl_xor(d, 16); d += __shfl_xor(d, 8); d += __shfl_xor(d, 4);
        d += __shfl_xor(d, 2);  d += __shfl_xor(d, 1);
        if (l32 == 0) wsc[wv][t] = d;
    }
    float acc = wsc[wv][lane] * 0.08838834764831845f;
    float m = acc;
#pragma unroll
    for (int off = 32; off; off >>= 1) m = fmaxf(m, __shfl_xor(m, off));
    const float e = __expf(acc - m), ets = e * t_sc;
    float se = e, sets = ets;
#pragma unroll
    for (int off = 32; off; off >>= 1) { se += __shfl_xor(se, off); sets += __shfl_xor(sets, off); }
    wsc[wv][lane] = ets / (sets + 1e-12f * se);
    const float* vbp = v + (size_t)h * SKV * HD;
    float4 o = make_float4(0.f, 0.f, 0.f, 0.f);
#pragma unroll 4
    for (int i = 0; i < TK / 2; ++i) {
        const int t = 2 * i + half, row = idxs[wv][t];
        const float wt = wsc[wv][t];
        float4 v4 = *(const float4*)(vbp + (size_t)row * HD + 4 * l32);
        o.x += wt * v4.x; o.y += wt * v4.y; o.z += wt * v4.z; o.w += wt * v4.w;
    }
    o.x += __shfl_xor(o.x, 32); o.y += __shfl_xor(o.y, 32);
    o.z += __shfl_xor(o.z, 32); o.w += __shfl_xor(o.w, 32);
    if (half == 0) *(float4*)(out + (size_t)(h * SQL + s) * HD + 4 * l32) = o;
}

extern "C" void kernel_launch(void* const* d_in, const int* in_sizes, int n_in,
                              void* d_out, int out_size, void* d_ws, size_t ws_size,
                              hipStream_t stream) {
    const float* q  = (const float*)d_in[0];
    const float* k  = (const float*)d_in[1];
    const float* v  = (const float*)d_in[2];
    const int*   ti = (const int*)d_in[3];
    const float* ts = (const float*)d_in[4];
    float* out = (float*)d_out;

    const size_t nkv  = (size_t)NH * SKV * HD;            // 8.4M elems each
    const size_t need = 2 * nkv * sizeof(unsigned short); // 33.6 MB
    if (ws_size >= need) {
        unsigned short* kh = (unsigned short*)d_ws;
        unsigned short* vh = kh + nkv;
        cvt_f16<<<dim3(8192), dim3(256), 0, stream>>>(k, v, kh, vh);
        dsa_phased<<<dim3(512), dim3(256), 0, stream>>>(q, kh, vh, ti, ts, out);
    } else {
        dsa_fp32<<<dim3(4096), dim3(256), 0, stream>>>(q, k, v, ti, ts, out);
    }
}